// Round 3
// baseline (544.426 us; speedup 1.0000x reference)
//
#include <hip/hip_runtime.h>
#include <stdint.h>

#define Bx 64
#define Tx 2048
#define ENCx 512
#define ATTx 256

typedef float f4 __attribute__((ext_vector_type(4)));
typedef float f32x4 __attribute__((ext_vector_type(4)));
typedef short bf16x8 __attribute__((ext_vector_type(8)));

__device__ __forceinline__ unsigned short f2bf(float f) {
  union { float f; uint32_t u; } c; c.f = f;
  uint32_t u = c.u;
  u += 0x7fffu + ((u >> 16) & 1u);   // RNE
  return (unsigned short)(u >> 16);
}

// pack two floats -> bf16 pair (round-to-nearest via +0x8000, then v_perm)
__device__ __forceinline__ uint32_t pk_bf(float lo, float hi) {
  uint32_t a = __float_as_uint(lo) + 0x8000u;
  uint32_t b = __float_as_uint(hi) + 0x8000u;
  return __builtin_amdgcn_perm(b, a, 0x07060302u);  // {hi16(b), hi16(a)}
}

__device__ __forceinline__ float ftanh(float x) {
  x = fminf(8.f, fmaxf(-8.f, x));
  float z = __expf(2.f * x);
  return 1.f - __fdividef(2.f, z + 1.f);
}

// K0: pack W_enc -> bf16, transposed + chunk-contiguous:
// WTc[(kc*256 + n)*32 + kk] = bf16(W_enc[(kc*32+kk)*256 + n])
__global__ void k0_wt(const float* __restrict__ W, unsigned short* __restrict__ WTc) {
  int tid = blockIdx.x * 256 + threadIdx.x;   // 131072 total
  int kc = tid >> 13;
  int r = tid & 8191;
  int n = r >> 5;
  int kk = r & 31;
  WTc[tid] = f2bf(W[(kc * 32 + kk) * ATTx + n]);
}

// K1: pd[b][a] = dec_hidden[b,:] @ W_dec[:,a]  (fp32)
__global__ void k1_pd(const float* __restrict__ dec, const float* __restrict__ Wd,
                      float* __restrict__ pd) {
  __shared__ float ld[512];
  int b = blockIdx.x, a = threadIdx.x;
  ld[a] = dec[b * 512 + a];
  ld[a + 256] = dec[b * 512 + a + 256];
  __syncthreads();
  float s = 0.f;
#pragma unroll 8
  for (int d = 0; d < 512; ++d) s = fmaf(ld[d], Wd[d * ATTx + a], s);
  pd[b * ATTx + a] = s;
}

// K2: energy[m] = v . tanh(enc[m,:] @ W_enc + pd[b,:])
// Wave = 32 rows x 64 cols (acc 32 VGPR) -> ~115 VGPR -> 4 waves/SIMD.
// A: global->reg with 1-chunk prefetch (4KB/wave in flight). B: L2-resident WTc.
__global__ __launch_bounds__(256, 4) void k2_energy(
    const float* __restrict__ enc, const unsigned short* __restrict__ WTc,
    const float* __restrict__ pd, const float* __restrict__ v,
    const int* __restrict__ mask, float* __restrict__ energy) {
  __shared__ float pdv[256];
  __shared__ float vvs[256];
  __shared__ float ep[4][32];
  const int tid = threadIdx.x;
  const int wid = tid >> 6;
  const int lane = tid & 63;
  const int q = lane >> 4;       // k-quad
  const int c15 = lane & 15;
  const int m0 = blockIdx.x * 32;        // 32 rows per block (all 4 waves)
  const int b = m0 >> 11;

  pdv[tid] = pd[b * ATTx + tid];
  vvs[tid] = v[tid];
  __syncthreads();

  // A pointers: lane covers rows {m0+c15, m0+16+c15}, k-offset q*8
  const float* a0 = enc + (size_t)(m0 + c15) * ENCx + q * 8;
  const float* a1 = a0 + 16 * ENCx;
  // B: this wave's 64 cols start at wid*64
  const unsigned short* wb = WTc + (wid * 64 + c15) * 32 + q * 8;

  f32x4 acc[2][4];
#pragma unroll
  for (int rt = 0; rt < 2; ++rt)
#pragma unroll
    for (int ct = 0; ct < 4; ++ct) { f32x4 z = {0.f,0.f,0.f,0.f}; acc[rt][ct] = z; }

  f4 cur0a = *(const f4*)(a0);
  f4 cur0b = *(const f4*)(a0 + 4);
  f4 cur1a = *(const f4*)(a1);
  f4 cur1b = *(const f4*)(a1 + 4);

#pragma unroll 4
  for (int kc = 0; kc < 16; ++kc) {
    f4 nxt0a, nxt0b, nxt1a, nxt1b;
    if (kc < 15) {
      const float* p0 = a0 + (kc + 1) * 32;
      const float* p1 = a1 + (kc + 1) * 32;
      nxt0a = *(const f4*)(p0);
      nxt0b = *(const f4*)(p0 + 4);
      nxt1a = *(const f4*)(p1);
      nxt1b = *(const f4*)(p1 + 4);
    }
    bf16x8 bfr[4];
    const unsigned short* wkc = wb + kc * 8192;
#pragma unroll
    for (int ct = 0; ct < 4; ++ct)
      bfr[ct] = *(const bf16x8*)(wkc + ct * 512);

    union { uint32_t u[4]; bf16x8 v; } am0, am1;
    am0.u[0] = pk_bf(cur0a.x, cur0a.y); am0.u[1] = pk_bf(cur0a.z, cur0a.w);
    am0.u[2] = pk_bf(cur0b.x, cur0b.y); am0.u[3] = pk_bf(cur0b.z, cur0b.w);
    am1.u[0] = pk_bf(cur1a.x, cur1a.y); am1.u[1] = pk_bf(cur1a.z, cur1a.w);
    am1.u[2] = pk_bf(cur1b.x, cur1b.y); am1.u[3] = pk_bf(cur1b.z, cur1b.w);

#pragma unroll
    for (int ct = 0; ct < 4; ++ct) {
      acc[0][ct] = __builtin_amdgcn_mfma_f32_16x16x32_bf16(am0.v, bfr[ct], acc[0][ct], 0, 0, 0);
      acc[1][ct] = __builtin_amdgcn_mfma_f32_16x16x32_bf16(am1.v, bfr[ct], acc[1][ct], 0, 0, 0);
    }
    cur0a = nxt0a; cur0b = nxt0b; cur1a = nxt1a; cur1b = nxt1b;
  }

  // epilogue: C/D layout col = c15 (within tile), row = q*4 + i
  float ps[2][4];
#pragma unroll
  for (int rt = 0; rt < 2; ++rt)
#pragma unroll
    for (int i = 0; i < 4; ++i) ps[rt][i] = 0.f;
#pragma unroll
  for (int ct = 0; ct < 4; ++ct) {
    int col = wid * 64 + ct * 16 + c15;
    float pv = pdv[col];
    float vv = vvs[col];
#pragma unroll
    for (int rt = 0; rt < 2; ++rt)
#pragma unroll
      for (int i = 0; i < 4; ++i)
        ps[rt][i] += ftanh(acc[rt][ct][i] + pv) * vv;
  }
#pragma unroll
  for (int s = 1; s < 16; s <<= 1)
#pragma unroll
    for (int rt = 0; rt < 2; ++rt)
#pragma unroll
      for (int i = 0; i < 4; ++i)
        ps[rt][i] += __shfl_xor(ps[rt][i], s, 64);
  if (c15 == 0)
#pragma unroll
    for (int rt = 0; rt < 2; ++rt)
#pragma unroll
      for (int i = 0; i < 4; ++i)
        ep[wid][rt * 16 + q * 4 + i] = ps[rt][i];
  __syncthreads();
  if (tid < 32) {
    float e = ep[0][tid] + ep[1][tid] + ep[2][tid] + ep[3][tid];
    int gm = m0 + tid;
    energy[gm] = mask[gm] ? -1e30f : e;
  }
}

// K3: per-b softmax over T with dead-row handling (nan_to_num -> 0)
__global__ void k3_softmax(const float* __restrict__ energy, float* __restrict__ attn) {
  __shared__ float redm[4];
  __shared__ float redl[4];
  int b = blockIdx.x, tid = threadIdx.x;
  int lane = tid & 63, wid = tid >> 6;
  float e[8];
#pragma unroll
  for (int i = 0; i < 8; ++i) e[i] = energy[b * Tx + tid + i * 256];
  float m = e[0];
#pragma unroll
  for (int i = 1; i < 8; ++i) m = fmaxf(m, e[i]);
#pragma unroll
  for (int s = 1; s < 64; s <<= 1) m = fmaxf(m, __shfl_xor(m, s, 64));
  if (lane == 0) redm[wid] = m;
  __syncthreads();
  m = fmaxf(fmaxf(redm[0], redm[1]), fmaxf(redm[2], redm[3]));
  bool dead = (m < -1e29f);
  float w[8];
  float l = 0.f;
#pragma unroll
  for (int i = 0; i < 8; ++i) { w[i] = dead ? 0.f : __expf(e[i] - m); l += w[i]; }
#pragma unroll
  for (int s = 1; s < 64; s <<= 1) l += __shfl_xor(l, s, 64);
  if (lane == 0) redl[wid] = l;
  __syncthreads();
  l = redl[0] + redl[1] + redl[2] + redl[3];
  float inv = dead ? 0.f : __fdividef(1.f, l);
#pragma unroll
  for (int i = 0; i < 8; ++i) attn[b * Tx + tid + i * 256] = w[i] * inv;
}

// K4: context partials over 32 T-chunks of 64:
// part[tc][b][e] = sum_{t in chunk} w[b,t] * enc[b,t,e]
// 8-deep load ILP -> HBM-bound.
__global__ __launch_bounds__(256) void k4_ctx(const float* __restrict__ enc,
                                              const float* __restrict__ attn,
                                              float* __restrict__ part) {
  __shared__ float wl[64];
  __shared__ f4 comb[128];
  int tc = blockIdx.x & 31, b = blockIdx.x >> 5;
  int tid = threadIdx.x;
  if (tid < 64) wl[tid] = attn[b * Tx + tc * 64 + tid];
  __syncthreads();
  int tg = tid >> 7;          // 0..1, each handles 32 t
  int ef = tid & 127;         // f4 index over 512 floats
  const f4* base = (const f4*)(enc + ((size_t)b * Tx + tc * 64 + tg * 32) * ENCx) + ef;
  f4 a = {0.f, 0.f, 0.f, 0.f};
#pragma unroll
  for (int j0 = 0; j0 < 32; j0 += 8) {
    f4 x[8];
#pragma unroll
    for (int u = 0; u < 8; ++u) x[u] = base[(size_t)(j0 + u) * 128];
#pragma unroll
    for (int u = 0; u < 8; ++u) a += x[u] * wl[tg * 32 + j0 + u];
  }
  if (tg == 1) comb[ef] = a;
  __syncthreads();
  if (tg == 0) {
    a += comb[ef];
    *((f4*)(part + ((size_t)tc * 64 + b) * 512) + ef) = a;
  }
}

// K5: context[b][e] = sum_tc part
__global__ void k5_red(const float* __restrict__ part, float* __restrict__ ctx) {
  int idx = blockIdx.x * 256 + threadIdx.x;   // 32768
  float s = 0.f;
#pragma unroll
  for (int tc = 0; tc < 32; ++tc) s += part[tc * 32768 + idx];
  ctx[idx] = s;
}

extern "C" void kernel_launch(void* const* d_in, const int* in_sizes, int n_in,
                              void* d_out, int out_size, void* d_ws, size_t ws_size,
                              hipStream_t stream) {
  const float* enc   = (const float*)d_in[0];
  const float* dec   = (const float*)d_in[1];
  const int*   mask  = (const int*)d_in[2];
  const float* W_enc = (const float*)d_in[3];
  const float* W_dec = (const float*)d_in[4];
  const float* v     = (const float*)d_in[5];
  float* ctx  = (float*)d_out;          // [64,512]
  float* attn = ctx + Bx * ENCx;        // [64,2048]
  char* ws = (char*)d_ws;
  unsigned short* WTc = (unsigned short*)ws;              // 262144 B
  float* pd     = (float*)(ws + 262144);                  // 65536 B
  float* energy = (float*)(ws + 262144 + 65536);          // 524288 B
  float* part   = (float*)(ws + 262144 + 65536 + 524288); // 4 MB

  k0_wt<<<512, 256, 0, stream>>>(W_enc, WTc);
  k1_pd<<<64, 256, 0, stream>>>(dec, W_dec, pd);
  k2_energy<<<4096, 256, 0, stream>>>(enc, WTc, pd, v, mask, energy);
  k3_softmax<<<64, 256, 0, stream>>>(energy, attn);
  k4_ctx<<<2048, 256, 0, stream>>>(enc, attn, part);
  k5_red<<<128, 256, 0, stream>>>(part, ctx);
}